// Round 7
// baseline (245.834 us; speedup 1.0000x reference)
//
#include <hip/hip_runtime.h>

#define Bdim 32
#define Tdim 256
#define Cdim 1024

typedef unsigned short u16;
typedef unsigned int u32;
typedef __bf16 bf16x8 __attribute__((ext_vector_type(8)));
typedef float f32x4 __attribute__((ext_vector_type(4)));

__device__ __forceinline__ float bf2f(u32 u) {
    union { u32 i; float f; } v; v.i = u << 16; return v.f;
}
__device__ __forceinline__ u16 f2bf(float f) {
    union { float f; u32 i; } v; v.f = f;
    u32 u = v.i;
    return (u16)((u + 0x7fffu + ((u >> 16) & 1u)) >> 16);  // RNE
}

__device__ __forceinline__ void gload16(const u16* g, u16* l) {
    __builtin_amdgcn_global_load_lds(
        (__attribute__((address_space(1))) const void*)g,
        (__attribute__((address_space(3))) void*)l, 16, 0, 0);
}

// ---- fused prep (x mixing -> bf16) + weight convert ---------------------------
__global__ __launch_bounds__(256) void prep_fused(
    const float* __restrict__ x, const float* __restrict__ tmk,
    const float* __restrict__ tmv, const float* __restrict__ tmr,
    u16* __restrict__ xk, u16* __restrict__ xv, u16* __restrict__ xr,
    const float* __restrict__ w0, const float* __restrict__ w1,
    const float* __restrict__ w2, const float* __restrict__ w3,
    u16* __restrict__ o0, u16* __restrict__ o1,
    u16* __restrict__ o2, u16* __restrict__ o3)
{
    int bid = blockIdx.x;
    if (bid < 4096) {
        int tid = bid * 256 + threadIdx.x;
        int e = tid << 3;
        int c = e & (Cdim - 1);
        int t = (e >> 10) & (Tdim - 1);
        float xf[8], xxf[8], mk[8], mv[8], mr[8];
        *(float4*)(xf)     = *(const float4*)(x + e);
        *(float4*)(xf + 4) = *(const float4*)(x + e + 4);
        if (t != 0) {
            *(float4*)(xxf)     = *(const float4*)(x + e - Cdim);
            *(float4*)(xxf + 4) = *(const float4*)(x + e - Cdim + 4);
        } else {
#pragma unroll
            for (int j = 0; j < 8; j++) xxf[j] = 0.f;
        }
        *(float4*)(mk)     = *(const float4*)(tmk + c);
        *(float4*)(mk + 4) = *(const float4*)(tmk + c + 4);
        *(float4*)(mv)     = *(const float4*)(tmv + c);
        *(float4*)(mv + 4) = *(const float4*)(tmv + c + 4);
        *(float4*)(mr)     = *(const float4*)(tmr + c);
        *(float4*)(mr + 4) = *(const float4*)(tmr + c + 4);
        u16 ok[8], ov[8], orr[8];
#pragma unroll
        for (int j = 0; j < 8; j++) {
            float d = xf[j] - xxf[j];
            ok[j]  = f2bf(xxf[j] + d * mk[j]);
            ov[j]  = f2bf(xxf[j] + d * mv[j]);
            orr[j] = f2bf(xxf[j] + d * mr[j]);
        }
        *(uint4*)(xk + e) = *(const uint4*)ok;
        *(uint4*)(xv + e) = *(const uint4*)ov;
        *(uint4*)(xr + e) = *(const uint4*)orr;
    } else {
        int wb = bid - 4096;                 // 0..2047
        int m = wb >> 9;                     // matrix 0..3
        const float* src; u16* dst;
        switch (m) {
            case 0: src = w0; dst = o0; break;
            case 1: src = w1; dst = o1; break;
            case 2: src = w2; dst = o2; break;
            default: src = w3; dst = o3; break;
        }
        int i = (((wb & 511) << 8) + threadIdx.x) << 3;
        float a[8];
        *(float4*)(a)     = *(const float4*)(src + i);
        *(float4*)(a + 4) = *(const float4*)(src + i + 4);
        u16 o[8];
#pragma unroll
        for (int j = 0; j < 8; j++) o[j] = f2bf(a[j]);
        *(uint4*)(dst + i) = *(const uint4*)o;
    }
}

// ---- GEMM body: C[8192,1024] = A[8192,1024] * Bw[1024,1024]^T (bf16 MFMA) -----
// r7 = r0's verified schedule + r6's verified geometry, composed:
//   tile 128(M)x256(N), 256 thr = 4 waves (2M x 2N), wave-tile 64x128
//   (acc[4][8]) -> LDS reads 1.46 KB/MFLOP vs r0's 2.19.
//   SINGLE-buffered 48 KiB LDS (r6's dbuf was the occupancy killer:
//   96 KiB -> 1 blk/CU -> 1 wave/SIMD -> fully exposed drains, 80 us).
//   48 KiB -> 3 blocks/CU co-resident (144<=160 KiB; VGPR ~136 -> 3
//   waves/SIMD <= 512-reg budget).  Grid 768 = ALL blocks resident at
//   once: zero tail + maximal m114 cross-block overlap to hide the
//   per-tile __syncthreads drain (what carries r0 at 2 blk/CU).
// Schedule per K-tile (m97/r0 pattern, race-safe):
//   stage(t) -> __syncthreads (drains vmcnt+lgkm, full fence) ->
//   compute(t) -> __syncthreads.
// ROTATION SWIZZLE (r0-verified, 0 conflicts): slot (row,pos) holds k-chunk
// (pos + ((row>>1)&3))&3; writer thread t fetches global chunk
// ((t&3)+((t>>3)&3))&3; reader lane (fr,quad) reads pos=(quad-((fr>>1)&3))&3.
template <int BF16OUT>
__device__ __forceinline__ void gemm_body(
    const u16* __restrict__ A, const u16* __restrict__ Bw, void* __restrict__ Cout,
    u16* __restrict__ Ls, int bm, int bn)
{
    const int K = Cdim, N = Cdim;
    const int NT = K / 64;                   // 16 K-tiles
    const int tid = threadIdx.x;
    const int lane = tid & 63, wave = tid >> 6;
    const int wm = (wave & 1) << 6;          // 0,64   (M)
    const int wn = (wave >> 1) << 7;         // 0,128  (N)
    const int fr = lane & 15, quad = lane >> 4;

    const int srow = tid >> 2;               // 0..63
    const int skc = ((((tid & 3) + ((tid >> 3) & 3)) & 3) << 3);  // rotated chunk
    const u16* ga = A + (size_t)(bm * 128 + srow) * K + skc;
    const u16* gb = Bw + (size_t)(bn * 256 + srow) * K + skc;
    const size_t gstep = (size_t)64 * K;     // +64 rows
    const int lw = wave << 9;                // wave-uniform LDS base (u16)

    // buffer layout (u16 offsets, 24576 u16 = 48 KB total):
    //   Ah0 [0,4096)  Bh0 [4096,12288)  Ah1 [12288,16384)  Bh1 [16384,24576)
    // each kstep-half: A = 128 rows x 32 k, B = 256 rows x 32 k, row-major
    // [row][32] with rotation chunks.
    auto stage = [&](int t) {
        const u16* gat = ga + t * 64;
        const u16* gbt = gb + t * 64;
        u16* base = Ls + lw;
        // kstep 0
        gload16(gat,              base);                 // A rows 0-63
        gload16(gat + gstep,      base + 2048);          // A rows 64-127
        gload16(gbt,              base + 4096);          // B rows 0-63
        gload16(gbt + gstep,      base + 4096 + 2048);   // B rows 64-127
        gload16(gbt + 2 * gstep,  base + 4096 + 4096);   // B rows 128-191
        gload16(gbt + 3 * gstep,  base + 4096 + 6144);   // B rows 192-255
        // kstep 1 (+32 k)
        gload16(gat + 32,             base + 12288);
        gload16(gat + 32 + gstep,     base + 12288 + 2048);
        gload16(gbt + 32,             base + 16384);
        gload16(gbt + 32 + gstep,     base + 16384 + 2048);
        gload16(gbt + 32 + 2 * gstep, base + 16384 + 4096);
        gload16(gbt + 32 + 3 * gstep, base + 16384 + 6144);
    };

    f32x4 acc[4][8];
#pragma unroll
    for (int i = 0; i < 4; i++)
#pragma unroll
        for (int j = 0; j < 8; j++)
            acc[i][j] = (f32x4){0.f, 0.f, 0.f, 0.f};

    const int rq = (((quad - ((fr >> 1) & 3)) & 3) << 3);  // reader pos (u16)

#pragma unroll 1
    for (int t = 0; t < NT; ++t) {
        stage(t);
        __syncthreads();                      // drains vmcnt + full fence
        __builtin_amdgcn_sched_barrier(0);
#pragma unroll
        for (int h = 0; h < 2; h++) {
            const u16* Ah = Ls + h * 12288;
            const u16* Bh = Ls + 4096 + h * 12288;
            bf16x8 af[4], bfr[8];
#pragma unroll
            for (int i = 0; i < 4; i++)
                af[i]  = *(const bf16x8*)(Ah + (wm + i * 16 + fr) * 32 + rq);
#pragma unroll
            for (int j = 0; j < 8; j++)
                bfr[j] = *(const bf16x8*)(Bh + (wn + j * 16 + fr) * 32 + rq);
#pragma unroll
            for (int i = 0; i < 4; i++)
#pragma unroll
                for (int j = 0; j < 8; j++)
                    acc[i][j] = __builtin_amdgcn_mfma_f32_16x16x32_bf16(
                        af[i], bfr[j], acc[i][j], 0, 0, 0);
        }
        __syncthreads();                      // reads done before next stage
        __builtin_amdgcn_sched_barrier(0);
    }

    // C/D layout: row = quad*4 + reg, col = lane&15  [m89-verified]
    const int gr0 = bm * 128 + wm + quad * 4;
    const int gc0 = bn * 256 + wn + fr;
#pragma unroll
    for (int i = 0; i < 4; i++)
#pragma unroll
        for (int j = 0; j < 8; j++)
#pragma unroll
            for (int r = 0; r < 4; r++) {
                int gr = gr0 + i * 16 + r;
                int gc = gc0 + j * 16;
                float val = acc[i][j][r];
                if (BF16OUT)
                    ((u16*)Cout)[(size_t)gr * N + gc] = f2bf(val);
                else
                    ((float*)Cout)[(size_t)gr * N + gc] = val;
            }
}

// grouped GEMM for k/v/r (blockIdx.z selects operand set), bf16 out
// XCD swizzle: bm = bx&63 -> XCD = bx%8 = bm%8, bn = bx>>6 (0..3): all 4
// bn-blocks sharing an A row-panel co-reside on one XCD.
__global__ __launch_bounds__(256, 2) void gemm3_kernel(
    const u16* __restrict__ xk, const u16* __restrict__ xv, const u16* __restrict__ xr,
    const u16* __restrict__ wk, const u16* __restrict__ wv, const u16* __restrict__ wr,
    u16* __restrict__ ck, u16* __restrict__ cv, u16* __restrict__ cr)
{
    __shared__ __align__(16) u16 Ls[24576];   // 48 KiB single buffer
    const u16* A; const u16* Bw; u16* Cout;
    switch (blockIdx.z) {
        case 0:  A = xk; Bw = wk; Cout = ck; break;
        case 1:  A = xv; Bw = wv; Cout = cv; break;
        default: A = xr; Bw = wr; Cout = cr; break;
    }
    int bx = blockIdx.x;
    gemm_body<1>(A, Bw, (void*)Cout, Ls, bx & 63, bx >> 6);
}

// final GEMM, f32 out
__global__ __launch_bounds__(256, 2) void gemmo_kernel(
    const u16* __restrict__ A, const u16* __restrict__ Bw, float* __restrict__ Cout)
{
    __shared__ __align__(16) u16 Ls[24576];
    int bx = blockIdx.x;
    gemm_body<0>(A, Bw, (void*)Cout, Ls, bx & 63, bx >> 6);
}

// ---- WKV scan + sigmoid(r) gate; register double-buffered prefetch ------------
#define WTC 16

#define LOADCHUNK(KA, VA, RA, T0)                                        \
    _Pragma("unroll")                                                    \
    for (int s = 0; s < WTC; s++) {                                      \
        size_t idx = base + (size_t)((T0) + s) * Cdim;                   \
        KA[s] = kb[idx]; VA[s] = vb[idx]; RA[s] = rb[idx];               \
    }

#define COMPCHUNK(KA, VA, RA, T0)                                        \
    _Pragma("unroll")                                                    \
    for (int s = 0; s < WTC; s++) {                                      \
        float kt = bf2f(KA[s]);                                          \
        float vt = bf2f(VA[s]);                                          \
        float rt = bf2f(RA[s]);                                          \
        float uk = u + kt;                                               \
        float no = fmaxf(o, uk);                                         \
        float Ae = __expf(o - no);                                       \
        float Bc = __expf(uk - no);                                      \
        float num = Ae * p + Bc * vt;                                    \
        float den = Ae * q + Bc;                                         \
        float y = num * __builtin_amdgcn_rcpf(den);                      \
        float sr = __builtin_amdgcn_rcpf(1.f + __expf(-rt));             \
        rwkv[base + (size_t)((T0) + s) * Cdim] = f2bf(y * sr);           \
        float wo = w + o;                                                \
        float no2 = fmaxf(wo, kt);                                       \
        float A2 = __expf(wo - no2);                                     \
        float B2 = __expf(kt - no2);                                     \
        p = A2 * p + B2 * vt;                                            \
        q = A2 * q + B2;                                                 \
        o = no2;                                                         \
    }

__global__ __launch_bounds__(64) void wkv_kernel(
    const u16* __restrict__ kb, const u16* __restrict__ vb,
    const u16* __restrict__ rb, const float* __restrict__ td,
    const float* __restrict__ tfirst, u16* __restrict__ rwkv)
{
    int lane = threadIdx.x;
    int blk = blockIdx.x;            // 512 blocks
    int b = blk >> 4;
    int c = ((blk & 15) << 6) + lane;
    float w = -__expf(td[c]);
    float u = tfirst[c];
    const size_t base = (size_t)b * Tdim * Cdim + c;

    u32 kA[WTC], vA[WTC], rA[WTC];
    u32 kB[WTC], vB[WTC], rB[WTC];
    float p = 0.f, q = 0.f, o = -1e38f;

    LOADCHUNK(kA, vA, rA, 0)
    for (int t0 = 0; t0 < Tdim; t0 += 2 * WTC) {
        LOADCHUNK(kB, vB, rB, t0 + WTC)
        COMPCHUNK(kA, vA, rA, t0)
        if (t0 + 2 * WTC < Tdim) {
            LOADCHUNK(kA, vA, rA, t0 + 2 * WTC)
        }
        COMPCHUNK(kB, vB, rB, t0 + WTC)
    }
}

extern "C" void kernel_launch(void* const* d_in, const int* in_sizes, int n_in,
                              void* d_out, int out_size, void* d_ws, size_t ws_size,
                              hipStream_t stream) {
    (void)in_sizes; (void)n_in; (void)out_size; (void)ws_size;
    const float* x   = (const float*)d_in[0];
    const float* td  = (const float*)d_in[1];
    const float* tfi = (const float*)d_in[2];
    const float* tmk = (const float*)d_in[3];
    const float* tmv = (const float*)d_in[4];
    const float* tmr = (const float*)d_in[5];
    const float* Wk  = (const float*)d_in[6];
    const float* Wv  = (const float*)d_in[7];
    const float* Wr  = (const float*)d_in[8];
    const float* Wo  = (const float*)d_in[9];

    char* ws = (char*)d_ws;
    const size_t MiB = (size_t)1 << 20;
    u16* xk    = (u16*)(ws);             // [0,16)
    u16* xv    = (u16*)(ws + 16 * MiB);  // [16,32)
    u16* xr    = (u16*)(ws + 32 * MiB);  // [32,48)
    u16* wkb   = (u16*)(ws + 48 * MiB);  // [48,50)
    u16* wvb   = (u16*)(ws + 50 * MiB);  // [50,52)
    u16* wrb   = (u16*)(ws + 52 * MiB);  // [52,54)
    u16* wob   = (u16*)(ws + 54 * MiB);  // [54,56)
    u16* kb    = (u16*)(ws + 56 * MiB);  // [56,72)
    u16* vb    = (u16*)(ws + 72 * MiB);  // [72,88)
    u16* rb    = (u16*)(ws + 88 * MiB);  // [88,104) — no alias: gemm3 z's run concurrently
    u16* rwkvb = (u16*)(ws);             // [0,16) — overlaps xk (dead after gemm3)

    prep_fused<<<6144, 256, 0, stream>>>(x, tmk, tmv, tmr, xk, xv, xr,
                                         Wk, Wv, Wr, Wo, wkb, wvb, wrb, wob);

    gemm3_kernel<<<dim3(256, 1, 3), 256, 0, stream>>>(xk, xv, xr, wkb, wvb, wrb,
                                                      kb, vb, rb);

    wkv_kernel<<<512, 64, 0, stream>>>(kb, vb, rb, td, tfi, rwkvb);

    gemmo_kernel<<<256, 256, 0, stream>>>(rwkvb, wob, (float*)d_out);
}

// Round 8
// 241.186 us; speedup vs baseline: 1.0193x; 1.0193x over previous
//
#include <hip/hip_runtime.h>

#define Bdim 32
#define Tdim 256
#define Cdim 1024

typedef unsigned short u16;
typedef unsigned int u32;
typedef __bf16 bf16x8 __attribute__((ext_vector_type(8)));
typedef float f32x4 __attribute__((ext_vector_type(4)));

__device__ __forceinline__ float bf2f(u32 u) {
    union { u32 i; float f; } v; v.i = u << 16; return v.f;
}
__device__ __forceinline__ u16 f2bf(float f) {
    union { float f; u32 i; } v; v.f = f;
    u32 u = v.i;
    return (u16)((u + 0x7fffu + ((u >> 16) & 1u)) >> 16);  // RNE
}

__device__ __forceinline__ void gload16(const u16* g, u16* l) {
    __builtin_amdgcn_global_load_lds(
        (__attribute__((address_space(1))) const void*)g,
        (__attribute__((address_space(3))) void*)l, 16, 0, 0);
}

// ---- fused prep (x mixing -> bf16) + weight convert ---------------------------
__global__ __launch_bounds__(256) void prep_fused(
    const float* __restrict__ x, const float* __restrict__ tmk,
    const float* __restrict__ tmv, const float* __restrict__ tmr,
    u16* __restrict__ xk, u16* __restrict__ xv, u16* __restrict__ xr,
    const float* __restrict__ w0, const float* __restrict__ w1,
    const float* __restrict__ w2, const float* __restrict__ w3,
    u16* __restrict__ o0, u16* __restrict__ o1,
    u16* __restrict__ o2, u16* __restrict__ o3)
{
    int bid = blockIdx.x;
    if (bid < 4096) {
        int tid = bid * 256 + threadIdx.x;
        int e = tid << 3;
        int c = e & (Cdim - 1);
        int t = (e >> 10) & (Tdim - 1);
        float xf[8], xxf[8], mk[8], mv[8], mr[8];
        *(float4*)(xf)     = *(const float4*)(x + e);
        *(float4*)(xf + 4) = *(const float4*)(x + e + 4);
        if (t != 0) {
            *(float4*)(xxf)     = *(const float4*)(x + e - Cdim);
            *(float4*)(xxf + 4) = *(const float4*)(x + e - Cdim + 4);
        } else {
#pragma unroll
            for (int j = 0; j < 8; j++) xxf[j] = 0.f;
        }
        *(float4*)(mk)     = *(const float4*)(tmk + c);
        *(float4*)(mk + 4) = *(const float4*)(tmk + c + 4);
        *(float4*)(mv)     = *(const float4*)(tmv + c);
        *(float4*)(mv + 4) = *(const float4*)(tmv + c + 4);
        *(float4*)(mr)     = *(const float4*)(tmr + c);
        *(float4*)(mr + 4) = *(const float4*)(tmr + c + 4);
        u16 ok[8], ov[8], orr[8];
#pragma unroll
        for (int j = 0; j < 8; j++) {
            float d = xf[j] - xxf[j];
            ok[j]  = f2bf(xxf[j] + d * mk[j]);
            ov[j]  = f2bf(xxf[j] + d * mv[j]);
            orr[j] = f2bf(xxf[j] + d * mr[j]);
        }
        *(uint4*)(xk + e) = *(const uint4*)ok;
        *(uint4*)(xv + e) = *(const uint4*)ov;
        *(uint4*)(xr + e) = *(const uint4*)orr;
    } else {
        int wb = bid - 4096;                 // 0..2047
        int m = wb >> 9;                     // matrix 0..3
        const float* src; u16* dst;
        switch (m) {
            case 0: src = w0; dst = o0; break;
            case 1: src = w1; dst = o1; break;
            case 2: src = w2; dst = o2; break;
            default: src = w3; dst = o3; break;
        }
        int i = (((wb & 511) << 8) + threadIdx.x) << 3;
        float a[8];
        *(float4*)(a)     = *(const float4*)(src + i);
        *(float4*)(a + 4) = *(const float4*)(src + i + 4);
        u16 o[8];
#pragma unroll
        for (int j = 0; j < 8; j++) o[j] = f2bf(a[j]);
        *(uint4*)(dst + i) = *(const uint4*)o;
    }
}

// ---- GEMM body: C[8192,1024] = A[8192,1024] * Bw[1024,1024]^T (bf16 MFMA) -----
// r4 EXACT (best measured: 62.4 us, MfmaUtil 33%, 2 blocks/CU) with one
// safety change: tile boundaries use __syncthreads() instead of manual
// asm drain + bare s_barrier.  Emitted waits are identical (vmcnt(0)+
// lgkmcnt(0) before barrier) but __syncthreads carries compiler fence
// semantics — r5 proved the bare-barrier pattern can race (stage hoisted
// above the barrier) depending on codegen.
// Structure: 128x128 tile, BK=64, 4 waves (2Mx2N, wave-tile 64x64),
// double-buffered LDS (2x32 KiB), one-tile-ahead prefetch: loop body =
// { stage(t+1, buf^1); compute(buf); __syncthreads(); }.
// ROTATION SWIZZLE (r0-verified, 0 bank conflicts): LDS slot (row,pos)
// holds k-chunk (pos+((row>>1)&3))&3; writer thread t fetches global chunk
// ((t&3)+((t>>3)&3))&3; reader lane (fr,quad) reads pos=(quad-((fr>>1)&3))&3.
template <int BF16OUT>
__device__ __forceinline__ void gemm_body(
    const u16* __restrict__ A, const u16* __restrict__ Bw, void* __restrict__ Cout,
    u16* __restrict__ Ls, int bm, int bn)
{
    const int K = Cdim, N = Cdim;
    const int NT = K / 64;                   // 16 K-tiles
    const int tid = threadIdx.x;
    const int lane = tid & 63, wave = tid >> 6;
    const int wm = (wave & 1) << 6, wn = (wave >> 1) << 6;
    const int fr = lane & 15, quad = lane >> 4;

    const int srow = tid >> 2;
    const int skc = ((((tid & 3) + ((tid >> 3) & 3)) & 3) << 3);  // rotated chunk
    const u16* ga = A + (size_t)(bm * 128 + srow) * K + skc;
    const u16* gb = Bw + (size_t)(bn * 128 + srow) * K + skc;
    const size_t gstep = (size_t)64 * K;
    const int lw = wave << 9;                // wave-uniform LDS base (u16)

    // buffer layout (u16 offsets within Ls):
    //   buf*16384 + { As0:0, Bs0:4096, As1:8192, Bs1:12288 } + lw + lane*8(HW)
    auto stage = [&](int t, int buf) {
        const u16* gat = ga + t * 64;
        const u16* gbt = gb + t * 64;
        u16* base = Ls + buf * 16384 + lw;
        gload16(gat,              base);
        gload16(gat + gstep,      base + 2048);
        gload16(gbt,              base + 4096);
        gload16(gbt + gstep,      base + 4096 + 2048);
        gload16(gat + 32,         base + 8192);
        gload16(gat + 32 + gstep, base + 8192 + 2048);
        gload16(gbt + 32,         base + 12288);
        gload16(gbt + 32 + gstep, base + 12288 + 2048);
    };

    f32x4 acc[4][4];
#pragma unroll
    for (int i = 0; i < 4; i++)
#pragma unroll
        for (int j = 0; j < 4; j++)
            acc[i][j] = (f32x4){0.f, 0.f, 0.f, 0.f};

    const int rq = (((quad - ((fr >> 1) & 3)) & 3) << 3);  // reader pos (u16)

    // prologue: stage tile 0; __syncthreads drains vmcnt + full fence
    stage(0, 0);
    __syncthreads();
    __builtin_amdgcn_sched_barrier(0);

#pragma unroll 1
    for (int t = 0; t < NT; ++t) {
        const int buf = t & 1;
        if (t + 1 < NT) stage(t + 1, buf ^ 1);   // prefetch next tile
        const u16* __restrict__ Tb = Ls + buf * 16384;
#pragma unroll
        for (int h = 0; h < 2; h++) {
            const u16* Ah = Tb + h * 8192;
            const u16* Bh = Tb + 4096 + h * 8192;
            bf16x8 af[4], bfr[4];
#pragma unroll
            for (int i = 0; i < 4; i++) {
                af[i]  = *(const bf16x8*)(Ah + (wm + i * 16 + fr) * 32 + rq);
                bfr[i] = *(const bf16x8*)(Bh + (wn + i * 16 + fr) * 32 + rq);
            }
#pragma unroll
            for (int i = 0; i < 4; i++)
#pragma unroll
                for (int j = 0; j < 4; j++)
                    acc[i][j] = __builtin_amdgcn_mfma_f32_16x16x32_bf16(
                        af[i], bfr[j], acc[i][j], 0, 0, 0);
        }
        // prefetch landed during compute; full drain + fence + barrier
        __syncthreads();
        __builtin_amdgcn_sched_barrier(0);
    }

    // C/D layout: row = quad*4 + reg, col = lane&15  [m89-verified]
    const int gr0 = bm * 128 + wm + quad * 4;
    const int gc0 = bn * 128 + wn + fr;
#pragma unroll
    for (int i = 0; i < 4; i++)
#pragma unroll
        for (int j = 0; j < 4; j++)
#pragma unroll
            for (int r = 0; r < 4; r++) {
                int gr = gr0 + i * 16 + r;
                int gc = gc0 + j * 16;
                float val = acc[i][j][r];
                if (BF16OUT)
                    ((u16*)Cout)[(size_t)gr * N + gc] = f2bf(val);
                else
                    ((float*)Cout)[(size_t)gr * N + gc] = val;
            }
}

// grouped GEMM for k/v/r (blockIdx.z selects operand set), bf16 out
// XCD swizzle: bm = x&63 -> XCD = x%8 = bm%8, so all 8 bn-blocks sharing an
// A row-block co-reside on one XCD (per-XCD L2 working set fits).
__global__ __launch_bounds__(256) void gemm3_kernel(
    const u16* __restrict__ xk, const u16* __restrict__ xv, const u16* __restrict__ xr,
    const u16* __restrict__ wk, const u16* __restrict__ wv, const u16* __restrict__ wr,
    u16* __restrict__ ck, u16* __restrict__ cv, u16* __restrict__ cr)
{
    __shared__ __align__(16) u16 Ls[2 * 16384];   // 64 KiB double buffer
    const u16* A; const u16* Bw; u16* Cout;
    switch (blockIdx.z) {
        case 0:  A = xk; Bw = wk; Cout = ck; break;
        case 1:  A = xv; Bw = wv; Cout = cv; break;
        default: A = xr; Bw = wr; Cout = cr; break;
    }
    int bx = blockIdx.x;
    gemm_body<1>(A, Bw, (void*)Cout, Ls, bx & 63, bx >> 6);
}

// final GEMM, f32 out
__global__ __launch_bounds__(256) void gemmo_kernel(
    const u16* __restrict__ A, const u16* __restrict__ Bw, float* __restrict__ Cout)
{
    __shared__ __align__(16) u16 Ls[2 * 16384];
    int bx = blockIdx.x;
    gemm_body<0>(A, Bw, (void*)Cout, Ls, bx & 63, bx >> 6);
}

// ---- WKV scan + sigmoid(r) gate --------------------------------------------
// 2 channels per thread via u32 loads (halves VMEM instruction count,
// 256B/wave-load instead of 128B) + TWO independent recurrence chains per
// thread (ILP-2 on the serial fmax/exp chain, the latency floor).
// 256 blocks x 64 threads -> 1 block/CU, every CU occupied.
#define WTC 16

#define LOADCHUNK2(KA, VA, RA, T0)                                       \
    _Pragma("unroll")                                                    \
    for (int s = 0; s < WTC; s++) {                                      \
        size_t idx = base32 + (size_t)((T0) + s) * cs;                   \
        KA[s] = k32[idx]; VA[s] = v32[idx]; RA[s] = r32[idx];            \
    }

#define COMPCHUNK2(KA, VA, RA, T0)                                       \
    _Pragma("unroll")                                                    \
    for (int s = 0; s < WTC; s++) {                                      \
        u32 kk = KA[s], vv = VA[s], rr = RA[s];                          \
        float kt0 = bf2f(kk), kt1 = bf2f(kk >> 16);                      \
        float vt0 = bf2f(vv), vt1 = bf2f(vv >> 16);                      \
        float rt0 = bf2f(rr), rt1 = bf2f(rr >> 16);                      \
        float uk0 = u0 + kt0,            uk1 = u1 + kt1;                 \
        float no0 = fmaxf(o0, uk0),      no1 = fmaxf(o1, uk1);           \
        float Ae0 = __expf(o0 - no0),    Ae1 = __expf(o1 - no1);         \
        float Bc0 = __expf(uk0 - no0),   Bc1 = __expf(uk1 - no1);        \
        float nm0 = Ae0 * p0 + Bc0 * vt0, nm1 = Ae1 * p1 + Bc1 * vt1;    \
        float dn0 = Ae0 * q0 + Bc0,      dn1 = Ae1 * q1 + Bc1;           \
        float y0 = nm0 * __builtin_amdgcn_rcpf(dn0);                     \
        float y1 = nm1 * __builtin_amdgcn_rcpf(dn1);                     \
        float sr0 = __builtin_amdgcn_rcpf(1.f + __expf(-rt0));           \
        float sr1 = __builtin_amdgcn_rcpf(1.f + __expf(-rt1));           \
        u32 pk = (u32)f2bf(y0 * sr0) | ((u32)f2bf(y1 * sr1) << 16);      \
        ow32[base32 + (size_t)((T0) + s) * cs] = pk;                     \
        float wo0 = w0 + o0,             wo1 = w1 + o1;                  \
        float n20 = fmaxf(wo0, kt0),     n21 = fmaxf(wo1, kt1);         \
        float A20 = __expf(wo0 - n20),   A21 = __expf(wo1 - n21);        \
        float B20 = __expf(kt0 - n20),   B21 = __expf(kt1 - n21);        \
        p0 = A20 * p0 + B20 * vt0;       p1 = A21 * p1 + B21 * vt1;      \
        q0 = A20 * q0 + B20;             q1 = A21 * q1 + B21;            \
        o0 = n20;                        o1 = n21;                       \
    }

__global__ __launch_bounds__(64) void wkv_kernel(
    const u16* __restrict__ kb, const u16* __restrict__ vb,
    const u16* __restrict__ rb, const float* __restrict__ td,
    const float* __restrict__ tfirst, u16* __restrict__ rwkv)
{
    int lane = threadIdx.x;
    int blk = blockIdx.x;            // 256 blocks
    int b = blk >> 3;                // batch 0..31
    int c = ((blk & 7) << 7) + (lane << 1);   // channel pair base
    float w0 = -__expf(td[c]),     w1 = -__expf(td[c + 1]);
    float u0 = tfirst[c],          u1 = tfirst[c + 1];
    const u32* k32 = (const u32*)kb;
    const u32* v32 = (const u32*)vb;
    const u32* r32 = (const u32*)rb;
    u32* ow32 = (u32*)rwkv;
    const size_t base32 = ((size_t)b * Tdim * Cdim + c) >> 1;
    const int cs = Cdim >> 1;        // u32 stride per t

    u32 kA[WTC], vA[WTC], rA[WTC];
    u32 kB[WTC], vB[WTC], rB[WTC];
    float p0 = 0.f, q0 = 0.f, o0 = -1e38f;
    float p1 = 0.f, q1 = 0.f, o1 = -1e38f;

    LOADCHUNK2(kA, vA, rA, 0)
    for (int t0 = 0; t0 < Tdim; t0 += 2 * WTC) {
        LOADCHUNK2(kB, vB, rB, t0 + WTC)
        COMPCHUNK2(kA, vA, rA, t0)
        if (t0 + 2 * WTC < Tdim) {
            LOADCHUNK2(kA, vA, rA, t0 + 2 * WTC)
        }
        COMPCHUNK2(kB, vB, rB, t0 + WTC)
    }
}

extern "C" void kernel_launch(void* const* d_in, const int* in_sizes, int n_in,
                              void* d_out, int out_size, void* d_ws, size_t ws_size,
                              hipStream_t stream) {
    (void)in_sizes; (void)n_in; (void)out_size; (void)ws_size;
    const float* x   = (const float*)d_in[0];
    const float* td  = (const float*)d_in[1];
    const float* tfi = (const float*)d_in[2];
    const float* tmk = (const float*)d_in[3];
    const float* tmv = (const float*)d_in[4];
    const float* tmr = (const float*)d_in[5];
    const float* Wk  = (const float*)d_in[6];
    const float* Wv  = (const float*)d_in[7];
    const float* Wr  = (const float*)d_in[8];
    const float* Wo  = (const float*)d_in[9];

    char* ws = (char*)d_ws;
    const size_t MiB = (size_t)1 << 20;
    u16* xk    = (u16*)(ws);             // [0,16)
    u16* xv    = (u16*)(ws + 16 * MiB);  // [16,32)
    u16* xr    = (u16*)(ws + 32 * MiB);  // [32,48)
    u16* wkb   = (u16*)(ws + 48 * MiB);  // [48,50)
    u16* wvb   = (u16*)(ws + 50 * MiB);  // [50,52)
    u16* wrb   = (u16*)(ws + 52 * MiB);  // [52,54)
    u16* wob   = (u16*)(ws + 54 * MiB);  // [54,56)
    u16* kb    = (u16*)(ws + 56 * MiB);  // [56,72)
    u16* vb    = (u16*)(ws + 72 * MiB);  // [72,88)
    u16* rb    = (u16*)(ws + 88 * MiB);  // [88,104) — no alias: gemm3 z's run concurrently
    u16* rwkvb = (u16*)(ws);             // [0,16) — overlaps xk (dead after gemm3)

    prep_fused<<<6144, 256, 0, stream>>>(x, tmk, tmv, tmr, xk, xv, xr,
                                         Wk, Wv, Wr, Wo, wkb, wvb, wrb, wob);

    gemm3_kernel<<<dim3(512, 1, 3), 256, 0, stream>>>(xk, xv, xr, wkb, wvb, wrb,
                                                      kb, vb, rb);

    wkv_kernel<<<256, 64, 0, stream>>>(kb, vb, rb, td, tfi, rwkvb);

    gemmo_kernel<<<512, 256, 0, stream>>>(rwkvb, wob, (float*)d_out);
}